// Round 5
// baseline (153.540 us; speedup 1.0000x reference)
//
#include <hip/hip_runtime.h>
#include <cmath>
#include <cstdint>
#include <cstddef>

#define NT 8192     // tokens
#define MD 4096     // model dim
#define NE 64       // experts
#define NCHUNK 128  // NT/64

// Output layout (all float32):
// [0] l_loss | gates_k[2][NT] | idx[2][NT] | locations[2][NT]
static constexpr int OFF_GATES = 1;
static constexpr int OFF_IDX   = 1 + 2 * NT;
static constexpr int OFF_LOC   = 1 + 4 * NT;

typedef __attribute__((ext_vector_type(8))) short short8_t;  // 8 bf16 (4 VGPR)
typedef __attribute__((ext_vector_type(4))) float f32x4;     // MFMA C/D

// Exact 3-way truncation split: x == h + m + s + r, |r| <= 2^-24 |x|.
__device__ __forceinline__ void split3(float v, short& h, short& m, short& s) {
  unsigned bx = __float_as_uint(v);
  h = (short)(bx >> 16);
  float r1 = v - __uint_as_float(bx & 0xFFFF0000u);
  unsigned b1 = __float_as_uint(r1);
  m = (short)(b1 >> 16);
  float r2 = r1 - __uint_as_float(b1 & 0xFFFF0000u);
  s = (short)(__float_as_uint(r2) >> 16);
}

// K0: precompute bf16 3-split of wg into workspace (done once per launch;
// B is tiny (1 MB) and L2/L3-resident for k1).
__global__ __launch_bounds__(256)
void k0_split(const float* __restrict__ wg, short* __restrict__ bh,
              short* __restrict__ bm, short* __restrict__ bs) {
  const int i = (blockIdx.x * 256 + threadIdx.x) * 4;   // NE*MD/4 threads
  float4 v = *(const float4*)(wg + i);
  short h0, m0, s0, h1, m1, s1, h2, m2, s2, h3, m3, s3;
  split3(v.x, h0, m0, s0); split3(v.y, h1, m1, s1);
  split3(v.z, h2, m2, s2); split3(v.w, h3, m3, s3);
  *(short4*)(bh + i) = make_short4(h0, h1, h2, h3);
  *(short4*)(bm + i) = make_short4(m0, m1, m2, m3);
  *(short4*)(bs + i) = make_short4(s0, s1, s2, s3);
}

// K1: logits-partial = x[64-token tile] . wg^T (all 64 experts) over a
// k-chunk via bf16 MFMA 3-split (6 term-pairs == fp32 accuracy).
// NO LDS, NO barriers: A fragment (row=lane&15, k=8*(lane>>4)+i — HW-validated
// rounds 3/4) loaded per-lane from global + split in-register; B fragments
// loaded pre-split from workspace (L2-hot). 4 free-running waves/block.
__global__ __launch_bounds__(256, 4)
void k1_gemm(const float* __restrict__ x, const short* __restrict__ bh,
             const short* __restrict__ bm, const short* __restrict__ bs,
             float* __restrict__ part, int kchunk) {
  const int lane = threadIdx.x & 63;
  const int w    = threadIdx.x >> 6;   // wave -> token group
  const int mt   = blockIdx.x;
  const int kc   = blockIdx.y * kchunk;
  const int row  = lane & 15;
  const int koct = lane >> 4;          // k-octet 0..3

  const int tok = mt * 64 + w * 16 + row;
  const float* ap = x + (size_t)tok * MD + kc + koct * 8;
  const size_t boff = (size_t)row * MD + kc + koct * 8;

  f32x4 acc[4];
#pragma unroll
  for (int n = 0; n < 4; ++n) acc[n] = (f32x4){0.f, 0.f, 0.f, 0.f};

  const int NS = kchunk / 32;
  for (int s = 0; s < NS; ++s) {
    float4 a0 = *(const float4*)(ap + s * 32);
    float4 a1 = *(const float4*)(ap + s * 32 + 4);
    float av[8] = {a0.x, a0.y, a0.z, a0.w, a1.x, a1.y, a1.z, a1.w};
    short8_t a_h, a_m, a_s;
#pragma unroll
    for (int i = 0; i < 8; ++i) {
      short h, m, q; split3(av[i], h, m, q);
      a_h[i] = h; a_m[i] = m; a_s[i] = q;
    }
#pragma unroll
    for (int n = 0; n < 4; ++n) {
      const size_t bo = boff + (size_t)n * 16 * MD + s * 32;
      short8_t b_h = *(const short8_t*)(bh + bo);
      short8_t b_m = *(const short8_t*)(bm + bo);
      short8_t b_s = *(const short8_t*)(bs + bo);
      acc[n] = __builtin_amdgcn_mfma_f32_16x16x32_bf16(a_h, b_h, acc[n], 0, 0, 0);
      acc[n] = __builtin_amdgcn_mfma_f32_16x16x32_bf16(a_h, b_m, acc[n], 0, 0, 0);
      acc[n] = __builtin_amdgcn_mfma_f32_16x16x32_bf16(a_m, b_h, acc[n], 0, 0, 0);
      acc[n] = __builtin_amdgcn_mfma_f32_16x16x32_bf16(a_h, b_s, acc[n], 0, 0, 0);
      acc[n] = __builtin_amdgcn_mfma_f32_16x16x32_bf16(a_s, b_h, acc[n], 0, 0, 0);
      acc[n] = __builtin_amdgcn_mfma_f32_16x16x32_bf16(a_m, b_m, acc[n], 0, 0, 0);
    }
  }

  // D layout (HW-validated): col = lane&15 (expert), row = 4*(lane>>4)+r (token)
  const int c   = blockIdx.y;
  const int col = lane & 15;
  const int rq  = lane >> 4;
#pragma unroll
  for (int n = 0; n < 4; ++n)
#pragma unroll
    for (int r = 0; r < 4; ++r) {
      const int dt = mt * 64 + w * 16 + rq * 4 + r;
      part[((size_t)c * NT + dt) * NE + n * 16 + col] = acc[n][r];
    }
}

// K2b: fold k-chunk partials (chunk-ascending, same order as before) +
// per-token top-2/softmax/gates/idx + per-chunk counts (transposed), in-chunk
// ranks (ballot/popcount), gate column sums (transposed). grid 128, block 64.
__global__ void k2b_topk(const float* __restrict__ part, float* __restrict__ out,
                         float* __restrict__ meT,
                         int* __restrict__ cntT0, int* __restrict__ cntT1,
                         int* __restrict__ rank0, int* __restrict__ rank1, int ks) {
  const int lane  = threadIdx.x;
  const int chunk = blockIdx.x;
  const int token = chunk * 64 + lane;

  float l[NE];
#pragma unroll
  for (int e = 0; e < NE; ++e) l[e] = 0.f;
  for (int c = 0; c < ks; ++c) {
    const float4* p4 = (const float4*)(part + ((size_t)c * NT + token) * NE);
#pragma unroll
    for (int q = 0; q < 16; ++q) {
      float4 v = p4[q];
      l[4*q+0] += v.x; l[4*q+1] += v.y; l[4*q+2] += v.z; l[4*q+3] += v.w;
    }
  }

  // jax tie-break (lowest index wins): strict > ascending scans
  float m1 = -INFINITY; int i1 = 0;
#pragma unroll
  for (int e = 0; e < NE; ++e) if (l[e] > m1) { m1 = l[e]; i1 = e; }
  float m2 = -INFINITY; int i2 = 0;
#pragma unroll
  for (int e = 0; e < NE; ++e) if (e != i1 && l[e] > m2) { m2 = l[e]; i2 = e; }

  float s = 0.f;
#pragma unroll
  for (int e = 0; e < NE; ++e) { l[e] = __expf(l[e] - m1); s += l[e]; }
  const float inv_s = 1.f / s;

  const float g2 = __expf(m2 - m1);   // normalized top-2: softmax denom cancels
  const float dn = 1.f + g2;
  out[OFF_GATES + token]      = 1.f / dn;
  out[OFF_GATES + NT + token] = g2 / dn;
  out[OFF_IDX + token]        = (float)i1;
  out[OFF_IDX + NT + token]   = (float)i2;

  const unsigned long long below = (1ULL << lane) - 1ULL;
  for (int e = 0; e < NE; ++e) {
    unsigned long long ma = __ballot(i1 == e);
    unsigned long long mb = __ballot(i2 == e);
    if (i1 == e) rank0[token] = __popcll(ma & below);
    if (i2 == e) rank1[token] = __popcll(mb & below);
    if (lane == e) {
      cntT0[lane * NCHUNK + chunk] = __popcll(ma);
      cntT1[lane * NCHUNK + chunk] = __popcll(mb);
    }
  }

  // column sums of softmax gates over this chunk (transpose via padded LDS)
  __shared__ float lds[64 * 65];
#pragma unroll
  for (int e = 0; e < NE; ++e) lds[lane * 65 + e] = l[e] * inv_s;
  __syncthreads();
  float col = 0.f;
#pragma unroll
  for (int t = 0; t < 64; ++t) col += lds[t * 65 + lane];
  meT[lane * NCHUNK + chunk] = col;   // lane = expert
}

// K3b: exclusive scan of per-chunk counts (k0 then k1 so k1 bases start at
// ce[e]); lane-contiguous (transposed) layout. me reduce + l_loss. 1 wave.
__global__ void k3b_scan(const int* __restrict__ cntT0, const int* __restrict__ cntT1,
                         int* __restrict__ baseT0, int* __restrict__ baseT1,
                         const float* __restrict__ meT, float* __restrict__ out) {
  const int e = threadIdx.x;
  const int* c0 = cntT0 + e * NCHUNK;
  const int* c1 = cntT1 + e * NCHUNK;
  int* b0 = baseT0 + e * NCHUNK;
  int* b1 = baseT1 + e * NCHUNK;
  int run = 0;
#pragma unroll 4
  for (int c = 0; c < NCHUNK; ++c) { b0[c] = run; run += c0[c]; }
  const int ce = run;
#pragma unroll 4
  for (int c = 0; c < NCHUNK; ++c) { b1[c] = run; run += c1[c]; }
  float me = 0.f;
  const float* mp = meT + e * NCHUNK;
#pragma unroll 4
  for (int c = 0; c < NCHUNK; ++c) me += mp[c];
  float v = me * (float)ce;
#pragma unroll
  for (int off = 1; off < 64; off <<= 1) v += __shfl_xor(v, off, 64);
  if (e == 0) out[0] = v * ((float)NE / ((float)NT * (float)NT));
}

// K3c: locations = chunk base + in-chunk rank. grid 128, block 64.
__global__ void k3c_loc(float* __restrict__ out,
                        const int* __restrict__ baseT0, const int* __restrict__ baseT1,
                        const int* __restrict__ rank0, const int* __restrict__ rank1) {
  const int lane  = threadIdx.x;
  const int chunk = blockIdx.x;
  const int token = chunk * 64 + lane;
  const int i1 = (int)out[OFF_IDX + token];
  const int i2 = (int)out[OFF_IDX + NT + token];
  out[OFF_LOC + token]      = (float)(baseT0[i1 * NCHUNK + chunk] + rank0[token]);
  out[OFF_LOC + NT + token] = (float)(baseT1[i2 * NCHUNK + chunk] + rank1[token]);
}

extern "C" void kernel_launch(void* const* d_in, const int* in_sizes, int n_in,
                              void* d_out, int out_size, void* d_ws, size_t ws_size,
                              hipStream_t stream) {
  const float* x  = (const float*)d_in[0];
  const float* wg = (const float*)d_in[1];
  float* out = (float*)d_out;

  const size_t bsplit_elems = (size_t)NE * MD;         // per split array
  const size_t fixed_bytes  = 3 * bsplit_elems * sizeof(short)   // Bh/Bm/Bs
                            + (5 * (size_t)NE * NCHUNK + 2 * NT) * 4;
  int ks = 8;   // 1024 k1 blocks = 4/CU
  while (ks > 1 &&
         fixed_bytes + (size_t)ks * NT * NE * sizeof(float) > ws_size)
    ks >>= 1;
  const int kchunk = MD / ks;

  short* bh   = (short*)d_ws;
  short* bm   = bh + bsplit_elems;
  short* bs   = bm + bsplit_elems;
  float* part = (float*)(bs + bsplit_elems);            // [ks][NT][NE]
  float* meT  = part + (size_t)ks * NT * NE;            // [64][128]
  int* cntT0  = (int*)(meT + NE * NCHUNK);
  int* cntT1  = cntT0 + NE * NCHUNK;
  int* baseT0 = cntT1 + NE * NCHUNK;
  int* baseT1 = baseT0 + NE * NCHUNK;
  int* rank0  = baseT1 + NE * NCHUNK;                   // [NT]
  int* rank1  = rank0 + NT;

  hipLaunchKernelGGL(k0_split, dim3(NE * MD / 1024), dim3(256), 0, stream,
                     wg, bh, bm, bs);
  hipLaunchKernelGGL(k1_gemm, dim3(NT / 64, ks), dim3(256), 0, stream,
                     x, bh, bm, bs, part, kchunk);
  hipLaunchKernelGGL(k2b_topk, dim3(NCHUNK), dim3(64), 0, stream,
                     part, out, meT, cntT0, cntT1, rank0, rank1, ks);
  hipLaunchKernelGGL(k3b_scan, dim3(1), dim3(64), 0, stream,
                     cntT0, cntT1, baseT0, baseT1, meT, out);
  hipLaunchKernelGGL(k3c_loc, dim3(NCHUNK), dim3(64), 0, stream,
                     out, baseT0, baseT1, rank0, rank1);
}

// Round 6
// 92.773 us; speedup vs baseline: 1.6550x; 1.6550x over previous
//
#include <hip/hip_runtime.h>
#include <cmath>
#include <cstdint>
#include <cstddef>

#define NT 8192     // tokens
#define MD 4096     // model dim
#define NE 64       // experts
#define NCHUNK 128  // NT/64

// Output layout (all float32):
// [0] l_loss | gates_k[2][NT] | idx[2][NT] | locations[2][NT]
static constexpr int OFF_GATES = 1;
static constexpr int OFF_IDX   = 1 + 2 * NT;
static constexpr int OFF_LOC   = 1 + 4 * NT;

typedef __attribute__((ext_vector_type(8))) short short8_t;  // 8 bf16 (4 VGPR)
typedef __attribute__((ext_vector_type(4))) float f32x4;     // MFMA C/D

// Exact 3-way truncation split: x == h + m + s + r, |r| <= 2^-24 |x|.
__device__ __forceinline__ void split3(float v, short& h, short& m, short& s) {
  unsigned bx = __float_as_uint(v);
  h = (short)(bx >> 16);
  float r1 = v - __uint_as_float(bx & 0xFFFF0000u);
  unsigned b1 = __float_as_uint(r1);
  m = (short)(b1 >> 16);
  float r2 = r1 - __uint_as_float(b1 & 0xFFFF0000u);
  s = (short)(__float_as_uint(r2) >> 16);
}

// K0: pack wg's bf16 3-split into MFMA B-fragment order:
// pkb[(sg*4+n)*3 + j][lane] (short8 each) so k1's B loads are base+lane*16,
// perfectly coalesced. B frag layout (HW-validated r3-r5): col=lane&15,
// k = sg*32 + 8*(lane>>4)+i. grid 512 (= 128 sg * 4 n), block 64.
__global__ __launch_bounds__(64)
void k0_pack(const float* __restrict__ wg, short8_t* __restrict__ pkb) {
  const int lane = threadIdx.x;
  const int n    = blockIdx.x & 3;
  const int sg   = blockIdx.x >> 2;          // k-step 0..127 over full MD
  const int e    = n * 16 + (lane & 15);
  const int k0   = sg * 32 + (lane >> 4) * 8;
  const float* src = wg + (size_t)e * MD + k0;
  float4 v0 = *(const float4*)(src);
  float4 v1 = *(const float4*)(src + 4);
  float av[8] = {v0.x, v0.y, v0.z, v0.w, v1.x, v1.y, v1.z, v1.w};
  short8_t h, m, s;
#pragma unroll
  for (int i = 0; i < 8; ++i) {
    short a, b, c; split3(av[i], a, b, c);
    h[i] = a; m[i] = b; s[i] = c;
  }
  short8_t* base = pkb + ((size_t)(sg * 4 + n) * 3) * 64 + lane;
  base[0]       = h;
  base[64]      = m;
  base[128]     = s;
}

// K1: logits-partial = x[64-token tile] . wg^T (all 64 experts) over a
// k-chunk via bf16 MFMA 3-split (6 term-pairs == fp32 accuracy).
// NO LDS, NO barriers. A fragment (row=lane&15, k=8*(lane>>4)+i) loaded
// per-lane from global + split in-register; B fragments loaded pre-packed
// (coalesced 1KB/instr, L1/L2-hot). 4 free-running waves/block, 4 blocks/CU.
__global__ __launch_bounds__(256, 4)
void k1_gemm(const float* __restrict__ x, const short8_t* __restrict__ pkb,
             float* __restrict__ part, int kchunk) {
  const int lane = threadIdx.x & 63;
  const int w    = threadIdx.x >> 6;   // wave -> token group
  const int mt   = blockIdx.x;
  const int kc   = blockIdx.y * kchunk;
  const int row  = lane & 15;
  const int koct = lane >> 4;          // k-octet 0..3

  const int tok = mt * 64 + w * 16 + row;
  const float* ap = x + (size_t)tok * MD + kc + koct * 8;

  f32x4 acc[4];
#pragma unroll
  for (int n = 0; n < 4; ++n) acc[n] = (f32x4){0.f, 0.f, 0.f, 0.f};

  const int sg0 = blockIdx.y * (kchunk / 32);
  const int NS  = kchunk / 32;
  for (int s = 0; s < NS; ++s) {
    float4 a0 = *(const float4*)(ap + s * 32);
    float4 a1 = *(const float4*)(ap + s * 32 + 4);
    float av[8] = {a0.x, a0.y, a0.z, a0.w, a1.x, a1.y, a1.z, a1.w};
    short8_t a_h, a_m, a_s;
#pragma unroll
    for (int i = 0; i < 8; ++i) {
      short h, m, q; split3(av[i], h, m, q);
      a_h[i] = h; a_m[i] = m; a_s[i] = q;
    }
    const size_t sgb = (size_t)(sg0 + s) * 4;
#pragma unroll
    for (int n = 0; n < 4; ++n) {
      const short8_t* bp = pkb + (sgb + n) * 3 * 64 + lane;
      short8_t b_h = bp[0];
      short8_t b_m = bp[64];
      short8_t b_s = bp[128];
      acc[n] = __builtin_amdgcn_mfma_f32_16x16x32_bf16(a_h, b_h, acc[n], 0, 0, 0);
      acc[n] = __builtin_amdgcn_mfma_f32_16x16x32_bf16(a_h, b_m, acc[n], 0, 0, 0);
      acc[n] = __builtin_amdgcn_mfma_f32_16x16x32_bf16(a_m, b_h, acc[n], 0, 0, 0);
      acc[n] = __builtin_amdgcn_mfma_f32_16x16x32_bf16(a_h, b_s, acc[n], 0, 0, 0);
      acc[n] = __builtin_amdgcn_mfma_f32_16x16x32_bf16(a_s, b_h, acc[n], 0, 0, 0);
      acc[n] = __builtin_amdgcn_mfma_f32_16x16x32_bf16(a_m, b_m, acc[n], 0, 0, 0);
    }
  }

  // D layout (HW-validated): col = lane&15 (expert), row = 4*(lane>>4)+r (token)
  const int c   = blockIdx.y;
  const int col = lane & 15;
  const int rq  = lane >> 4;
#pragma unroll
  for (int n = 0; n < 4; ++n)
#pragma unroll
    for (int r = 0; r < 4; ++r) {
      const int dt = mt * 64 + w * 16 + rq * 4 + r;
      part[((size_t)c * NT + dt) * NE + n * 16 + col] = acc[n][r];
    }
}

// K2b: fold k-chunk partials (chunk-ascending) + per-token top-2/softmax/
// gates/idx + per-chunk counts (transposed), in-chunk ranks, gate column
// sums (transposed). grid 128, block 64.
__global__ void k2b_topk(const float* __restrict__ part, float* __restrict__ out,
                         float* __restrict__ meT,
                         int* __restrict__ cntT0, int* __restrict__ cntT1,
                         int* __restrict__ rank0, int* __restrict__ rank1, int ks) {
  const int lane  = threadIdx.x;
  const int chunk = blockIdx.x;
  const int token = chunk * 64 + lane;

  float l[NE];
#pragma unroll
  for (int e = 0; e < NE; ++e) l[e] = 0.f;
  for (int c = 0; c < ks; ++c) {
    const float4* p4 = (const float4*)(part + ((size_t)c * NT + token) * NE);
#pragma unroll
    for (int q = 0; q < 16; ++q) {
      float4 v = p4[q];
      l[4*q+0] += v.x; l[4*q+1] += v.y; l[4*q+2] += v.z; l[4*q+3] += v.w;
    }
  }

  // jax tie-break (lowest index wins): strict > ascending scans
  float m1 = -INFINITY; int i1 = 0;
#pragma unroll
  for (int e = 0; e < NE; ++e) if (l[e] > m1) { m1 = l[e]; i1 = e; }
  float m2 = -INFINITY; int i2 = 0;
#pragma unroll
  for (int e = 0; e < NE; ++e) if (e != i1 && l[e] > m2) { m2 = l[e]; i2 = e; }

  float s = 0.f;
#pragma unroll
  for (int e = 0; e < NE; ++e) { l[e] = __expf(l[e] - m1); s += l[e]; }
  const float inv_s = 1.f / s;

  const float g2 = __expf(m2 - m1);   // normalized top-2: softmax denom cancels
  const float dn = 1.f + g2;
  out[OFF_GATES + token]      = 1.f / dn;
  out[OFF_GATES + NT + token] = g2 / dn;
  out[OFF_IDX + token]        = (float)i1;
  out[OFF_IDX + NT + token]   = (float)i2;

  const unsigned long long below = (1ULL << lane) - 1ULL;
  for (int e = 0; e < NE; ++e) {
    unsigned long long ma = __ballot(i1 == e);
    unsigned long long mb = __ballot(i2 == e);
    if (i1 == e) rank0[token] = __popcll(ma & below);
    if (i2 == e) rank1[token] = __popcll(mb & below);
    if (lane == e) {
      cntT0[lane * NCHUNK + chunk] = __popcll(ma);
      cntT1[lane * NCHUNK + chunk] = __popcll(mb);
    }
  }

  // column sums of softmax gates over this chunk (transpose via padded LDS)
  __shared__ float lds[64 * 65];
#pragma unroll
  for (int e = 0; e < NE; ++e) lds[lane * 65 + e] = l[e] * inv_s;
  __syncthreads();
  float col = 0.f;
#pragma unroll
  for (int t = 0; t < 64; ++t) col += lds[t * 65 + lane];
  meT[lane * NCHUNK + chunk] = col;   // lane = expert
}

// K3b: exclusive scan of per-chunk counts (k0 then k1 so k1 bases start at
// ce[e]); lane-contiguous (transposed) layout. me reduce + l_loss. 1 wave.
__global__ void k3b_scan(const int* __restrict__ cntT0, const int* __restrict__ cntT1,
                         int* __restrict__ baseT0, int* __restrict__ baseT1,
                         const float* __restrict__ meT, float* __restrict__ out) {
  const int e = threadIdx.x;
  const int* c0 = cntT0 + e * NCHUNK;
  const int* c1 = cntT1 + e * NCHUNK;
  int* b0 = baseT0 + e * NCHUNK;
  int* b1 = baseT1 + e * NCHUNK;
  int run = 0;
#pragma unroll 4
  for (int c = 0; c < NCHUNK; ++c) { b0[c] = run; run += c0[c]; }
  const int ce = run;
#pragma unroll 4
  for (int c = 0; c < NCHUNK; ++c) { b1[c] = run; run += c1[c]; }
  float me = 0.f;
  const float* mp = meT + e * NCHUNK;
#pragma unroll 4
  for (int c = 0; c < NCHUNK; ++c) me += mp[c];
  float v = me * (float)ce;
#pragma unroll
  for (int off = 1; off < 64; off <<= 1) v += __shfl_xor(v, off, 64);
  if (e == 0) out[0] = v * ((float)NE / ((float)NT * (float)NT));
}

// K3c: locations = chunk base + in-chunk rank. grid 128, block 64.
__global__ void k3c_loc(float* __restrict__ out,
                        const int* __restrict__ baseT0, const int* __restrict__ baseT1,
                        const int* __restrict__ rank0, const int* __restrict__ rank1) {
  const int lane  = threadIdx.x;
  const int chunk = blockIdx.x;
  const int token = chunk * 64 + lane;
  const int i1 = (int)out[OFF_IDX + token];
  const int i2 = (int)out[OFF_IDX + NT + token];
  out[OFF_LOC + token]      = (float)(baseT0[i1 * NCHUNK + chunk] + rank0[token]);
  out[OFF_LOC + NT + token] = (float)(baseT1[i2 * NCHUNK + chunk] + rank1[token]);
}

extern "C" void kernel_launch(void* const* d_in, const int* in_sizes, int n_in,
                              void* d_out, int out_size, void* d_ws, size_t ws_size,
                              hipStream_t stream) {
  const float* x  = (const float*)d_in[0];
  const float* wg = (const float*)d_in[1];
  float* out = (float*)d_out;

  const size_t pkb_sl = (size_t)NCHUNK * 4 * 3 * 64;   // short8 slots (1.5 MB)
  const size_t fixed_bytes = pkb_sl * 16
                           + (5 * (size_t)NE * NCHUNK + 2 * NT) * 4;
  int ks = 8;   // 1024 k1 blocks = 4/CU
  while (ks > 1 &&
         fixed_bytes + (size_t)ks * NT * NE * sizeof(float) > ws_size)
    ks >>= 1;
  const int kchunk = MD / ks;

  short8_t* pkb = (short8_t*)d_ws;
  float* part = (float*)((char*)d_ws + pkb_sl * 16);    // [ks][NT][NE]
  float* meT  = part + (size_t)ks * NT * NE;            // [64][128]
  int* cntT0  = (int*)(meT + NE * NCHUNK);
  int* cntT1  = cntT0 + NE * NCHUNK;
  int* baseT0 = cntT1 + NE * NCHUNK;
  int* baseT1 = baseT0 + NE * NCHUNK;
  int* rank0  = baseT1 + NE * NCHUNK;                   // [NT]
  int* rank1  = rank0 + NT;

  hipLaunchKernelGGL(k0_pack, dim3(NCHUNK * 4), dim3(64), 0, stream, wg, pkb);
  hipLaunchKernelGGL(k1_gemm, dim3(NT / 64, ks), dim3(256), 0, stream,
                     x, pkb, part, kchunk);
  hipLaunchKernelGGL(k2b_topk, dim3(NCHUNK), dim3(64), 0, stream,
                     part, out, meT, cntT0, cntT1, rank0, rank1, ks);
  hipLaunchKernelGGL(k3b_scan, dim3(1), dim3(64), 0, stream,
                     cntT0, cntT1, baseT0, baseT1, meT, out);
  hipLaunchKernelGGL(k3c_loc, dim3(NCHUNK), dim3(64), 0, stream,
                     out, baseT0, baseT1, rank0, rank1);
}

// Round 7
// 92.335 us; speedup vs baseline: 1.6629x; 1.0047x over previous
//
#include <hip/hip_runtime.h>
#include <cmath>
#include <cstdint>
#include <cstddef>

#define NT 8192     // tokens
#define MD 4096     // model dim
#define NE 64       // experts
#define NCHUNK 128  // NT/64

// Output layout (all float32):
// [0] l_loss | gates_k[2][NT] | idx[2][NT] | locations[2][NT]
static constexpr int OFF_GATES = 1;
static constexpr int OFF_IDX   = 1 + 2 * NT;
static constexpr int OFF_LOC   = 1 + 4 * NT;

typedef __attribute__((ext_vector_type(8))) short short8_t;  // 8 bf16 (4 VGPR)
typedef __attribute__((ext_vector_type(4))) float f32x4;     // MFMA C/D

// Exact 3-way truncation split: x == h + m + s + r, |r| <= 2^-24 |x|.
__device__ __forceinline__ void split3(float v, short& h, short& m, short& s) {
  unsigned bx = __float_as_uint(v);
  h = (short)(bx >> 16);
  float r1 = v - __uint_as_float(bx & 0xFFFF0000u);
  unsigned b1 = __float_as_uint(r1);
  m = (short)(b1 >> 16);
  float r2 = r1 - __uint_as_float(b1 & 0xFFFF0000u);
  s = (short)(__float_as_uint(r2) >> 16);
}

// K0: pack wg's bf16 3-split into MFMA B-fragment order:
// pkb[((sg*4+n)*3+j)*64 + lane] (short8 each) so k1's B loads are
// base+lane*16, perfectly coalesced. B frag layout (HW-validated r3-r6):
// col=lane&15, k = sg*32 + 8*(lane>>4)+i. grid 512 (=128 sg * 4 n), block 64.
__global__ __launch_bounds__(64)
void k0_pack(const float* __restrict__ wg, short8_t* __restrict__ pkb) {
  const int lane = threadIdx.x;
  const int n    = blockIdx.x & 3;
  const int sg   = blockIdx.x >> 2;          // k-step 0..127 over full MD
  const int e    = n * 16 + (lane & 15);
  const int k0   = sg * 32 + (lane >> 4) * 8;
  const float* src = wg + (size_t)e * MD + k0;
  float4 v0 = *(const float4*)(src);
  float4 v1 = *(const float4*)(src + 4);
  float av[8] = {v0.x, v0.y, v0.z, v0.w, v1.x, v1.y, v1.z, v1.w};
  short8_t h, m, s;
#pragma unroll
  for (int i = 0; i < 8; ++i) {
    short a, b, c; split3(av[i], a, b, c);
    h[i] = a; m[i] = b; s[i] = c;
  }
  short8_t* base = pkb + ((size_t)(sg * 4 + n) * 3) * 64 + lane;
  base[0]   = h;
  base[64]  = m;
  base[128] = s;
}

// K1: logits-partial = x[64-token tile] . wg^T (all 64 experts) over a
// k-chunk via bf16 MFMA 3-split (6 term-pairs == fp32 accuracy).
// NO LDS, NO barriers. Explicit register software-pipeline:
//   - A tile (2x float4/step) prefetched at DEPTH 2; prefetch issued AFTER
//     the step's B-loads so the MFMA's vmcnt wait (B) leaves A in flight.
//   - 12 B fragments/step loaded to regs at step top (coalesced, L2-hot).
// Fully-unrolled NS loop => all slot vars static (no scratch).
template <int NS>
__global__ __launch_bounds__(256, 4)
void k1_gemm(const float* __restrict__ x, const short8_t* __restrict__ pkb,
             float* __restrict__ part) {
  const int lane  = threadIdx.x & 63;
  const int w     = threadIdx.x >> 6;   // wave -> token group
  const int mt    = blockIdx.x;
  const int chunk = blockIdx.y;
  const int kc    = chunk * NS * 32;
  const int row   = lane & 15;
  const int koct  = lane >> 4;          // k-octet 0..3

  const int tok = mt * 64 + w * 16 + row;
  const float* ap = x + (size_t)tok * MD + kc + koct * 8;
  const short8_t* bbase = pkb + (size_t)chunk * NS * 12 * 64 + lane;

  f32x4 acc[4];
#pragma unroll
  for (int n = 0; n < 4; ++n) acc[n] = (f32x4){0.f, 0.f, 0.f, 0.f};

  auto lda = [&](int s, float4& r0, float4& r1) {
    const float4* p = (const float4*)(ap + s * 32);
    r0 = p[0];
    r1 = p[1];
  };

  // One k-step: B-loads -> (optional A prefetch for s+2) -> split A -> MFMA.
  auto step = [&](int s, float4 a0, float4 a1, bool pre, int ps,
                  float4* pr0, float4* pr1) {
    const short8_t* bp = bbase + (size_t)s * 12 * 64;
    short8_t bh[4], bm[4], bq[4];
#pragma unroll
    for (int n = 0; n < 4; ++n) {
      bh[n] = bp[n * 3 * 64];
      bm[n] = bp[n * 3 * 64 + 64];
      bq[n] = bp[n * 3 * 64 + 128];
    }
    if (pre) lda(ps, *pr0, *pr1);       // issued after B: stays in flight 2 steps
    float av[8] = {a0.x, a0.y, a0.z, a0.w, a1.x, a1.y, a1.z, a1.w};
    short8_t a_h, a_m, a_s;
#pragma unroll
    for (int i = 0; i < 8; ++i) {
      short h, m, q; split3(av[i], h, m, q);
      a_h[i] = h; a_m[i] = m; a_s[i] = q;
    }
#pragma unroll
    for (int n = 0; n < 4; ++n) {       // exact same term order as r5/r6 (absmax 0)
      acc[n] = __builtin_amdgcn_mfma_f32_16x16x32_bf16(a_h, bh[n], acc[n], 0, 0, 0);
      acc[n] = __builtin_amdgcn_mfma_f32_16x16x32_bf16(a_h, bm[n], acc[n], 0, 0, 0);
      acc[n] = __builtin_amdgcn_mfma_f32_16x16x32_bf16(a_m, bh[n], acc[n], 0, 0, 0);
      acc[n] = __builtin_amdgcn_mfma_f32_16x16x32_bf16(a_h, bq[n], acc[n], 0, 0, 0);
      acc[n] = __builtin_amdgcn_mfma_f32_16x16x32_bf16(a_s, bh[n], acc[n], 0, 0, 0);
      acc[n] = __builtin_amdgcn_mfma_f32_16x16x32_bf16(a_m, bm[n], acc[n], 0, 0, 0);
    }
  };

  float4 c0, c1, n0, n1, p0, p1, q0, q1;
  lda(0, c0, c1);
  lda(1, n0, n1);
#pragma unroll
  for (int s = 0; s < NS; s += 2) {     // full unroll: flags/indices constant
    step(s,     c0, c1, s + 2 < NS, s + 2, &p0, &p1);
    step(s + 1, n0, n1, s + 3 < NS, s + 3, &q0, &q1);
    c0 = p0; c1 = p1; n0 = q0; n1 = q1;
  }

  // D layout (HW-validated): col = lane&15 (expert), row = 4*(lane>>4)+r (token)
  const int col = lane & 15;
  const int rq  = lane >> 4;
#pragma unroll
  for (int n = 0; n < 4; ++n)
#pragma unroll
    for (int r = 0; r < 4; ++r) {
      const int dt = mt * 64 + w * 16 + rq * 4 + r;
      part[((size_t)chunk * NT + dt) * NE + n * 16 + col] = acc[n][r];
    }
}

// K2b: fold k-chunk partials (chunk-ascending) + per-token top-2/softmax/
// gates/idx + per-chunk counts (transposed), in-chunk ranks, gate column
// sums (transposed). grid 128, block 64.
__global__ void k2b_topk(const float* __restrict__ part, float* __restrict__ out,
                         float* __restrict__ meT,
                         int* __restrict__ cntT0, int* __restrict__ cntT1,
                         int* __restrict__ rank0, int* __restrict__ rank1, int ks) {
  const int lane  = threadIdx.x;
  const int chunk = blockIdx.x;
  const int token = chunk * 64 + lane;

  float l[NE];
#pragma unroll
  for (int e = 0; e < NE; ++e) l[e] = 0.f;
  for (int c = 0; c < ks; ++c) {
    const float4* p4 = (const float4*)(part + ((size_t)c * NT + token) * NE);
#pragma unroll
    for (int q = 0; q < 16; ++q) {
      float4 v = p4[q];
      l[4*q+0] += v.x; l[4*q+1] += v.y; l[4*q+2] += v.z; l[4*q+3] += v.w;
    }
  }

  // jax tie-break (lowest index wins): strict > ascending scans
  float m1 = -INFINITY; int i1 = 0;
#pragma unroll
  for (int e = 0; e < NE; ++e) if (l[e] > m1) { m1 = l[e]; i1 = e; }
  float m2 = -INFINITY; int i2 = 0;
#pragma unroll
  for (int e = 0; e < NE; ++e) if (e != i1 && l[e] > m2) { m2 = l[e]; i2 = e; }

  float s = 0.f;
#pragma unroll
  for (int e = 0; e < NE; ++e) { l[e] = __expf(l[e] - m1); s += l[e]; }
  const float inv_s = 1.f / s;

  const float g2 = __expf(m2 - m1);   // normalized top-2: softmax denom cancels
  const float dn = 1.f + g2;
  out[OFF_GATES + token]      = 1.f / dn;
  out[OFF_GATES + NT + token] = g2 / dn;
  out[OFF_IDX + token]        = (float)i1;
  out[OFF_IDX + NT + token]   = (float)i2;

  const unsigned long long below = (1ULL << lane) - 1ULL;
  for (int e = 0; e < NE; ++e) {
    unsigned long long ma = __ballot(i1 == e);
    unsigned long long mb = __ballot(i2 == e);
    if (i1 == e) rank0[token] = __popcll(ma & below);
    if (i2 == e) rank1[token] = __popcll(mb & below);
    if (lane == e) {
      cntT0[lane * NCHUNK + chunk] = __popcll(ma);
      cntT1[lane * NCHUNK + chunk] = __popcll(mb);
    }
  }

  // column sums of softmax gates over this chunk (transpose via padded LDS)
  __shared__ float lds[64 * 65];
#pragma unroll
  for (int e = 0; e < NE; ++e) lds[lane * 65 + e] = l[e] * inv_s;
  __syncthreads();
  float col = 0.f;
#pragma unroll
  for (int t = 0; t < 64; ++t) col += lds[t * 65 + lane];
  meT[lane * NCHUNK + chunk] = col;   // lane = expert
}

// K3b: exclusive scan of per-chunk counts (k0 then k1 so k1 bases start at
// ce[e]); lane-contiguous (transposed) layout. me reduce + l_loss. 1 wave.
__global__ void k3b_scan(const int* __restrict__ cntT0, const int* __restrict__ cntT1,
                         int* __restrict__ baseT0, int* __restrict__ baseT1,
                         const float* __restrict__ meT, float* __restrict__ out) {
  const int e = threadIdx.x;
  const int* c0 = cntT0 + e * NCHUNK;
  const int* c1 = cntT1 + e * NCHUNK;
  int* b0 = baseT0 + e * NCHUNK;
  int* b1 = baseT1 + e * NCHUNK;
  int run = 0;
#pragma unroll 4
  for (int c = 0; c < NCHUNK; ++c) { b0[c] = run; run += c0[c]; }
  const int ce = run;
#pragma unroll 4
  for (int c = 0; c < NCHUNK; ++c) { b1[c] = run; run += c1[c]; }
  float me = 0.f;
  const float* mp = meT + e * NCHUNK;
#pragma unroll 4
  for (int c = 0; c < NCHUNK; ++c) me += mp[c];
  float v = me * (float)ce;
#pragma unroll
  for (int off = 1; off < 64; off <<= 1) v += __shfl_xor(v, off, 64);
  if (e == 0) out[0] = v * ((float)NE / ((float)NT * (float)NT));
}

// K3c: locations = chunk base + in-chunk rank. grid 128, block 64.
__global__ void k3c_loc(float* __restrict__ out,
                        const int* __restrict__ baseT0, const int* __restrict__ baseT1,
                        const int* __restrict__ rank0, const int* __restrict__ rank1) {
  const int lane  = threadIdx.x;
  const int chunk = blockIdx.x;
  const int token = chunk * 64 + lane;
  const int i1 = (int)out[OFF_IDX + token];
  const int i2 = (int)out[OFF_IDX + NT + token];
  out[OFF_LOC + token]      = (float)(baseT0[i1 * NCHUNK + chunk] + rank0[token]);
  out[OFF_LOC + NT + token] = (float)(baseT1[i2 * NCHUNK + chunk] + rank1[token]);
}

extern "C" void kernel_launch(void* const* d_in, const int* in_sizes, int n_in,
                              void* d_out, int out_size, void* d_ws, size_t ws_size,
                              hipStream_t stream) {
  const float* x  = (const float*)d_in[0];
  const float* wg = (const float*)d_in[1];
  float* out = (float*)d_out;

  const size_t pkb_sl = (size_t)NCHUNK * 4 * 3 * 64;   // short8 slots (1.5 MB)
  const size_t fixed_bytes = pkb_sl * 16
                           + (5 * (size_t)NE * NCHUNK + 2 * NT) * 4;
  int ks = 8;   // 1024 k1 blocks = 4/CU
  while (ks > 4 &&
         fixed_bytes + (size_t)ks * NT * NE * sizeof(float) > ws_size)
    ks >>= 1;
  const int kchunk_unused = MD / ks; (void)kchunk_unused;

  short8_t* pkb = (short8_t*)d_ws;
  float* part = (float*)((char*)d_ws + pkb_sl * 16);    // [ks][NT][NE]
  float* meT  = part + (size_t)ks * NT * NE;            // [64][128]
  int* cntT0  = (int*)(meT + NE * NCHUNK);
  int* cntT1  = cntT0 + NE * NCHUNK;
  int* baseT0 = cntT1 + NE * NCHUNK;
  int* baseT1 = baseT0 + NE * NCHUNK;
  int* rank0  = baseT1 + NE * NCHUNK;                   // [NT]
  int* rank1  = rank0 + NT;

  hipLaunchKernelGGL(k0_pack, dim3(NCHUNK * 4), dim3(64), 0, stream, wg, pkb);
  if (ks == 8)
    hipLaunchKernelGGL((k1_gemm<16>), dim3(NT / 64, 8), dim3(256), 0, stream,
                       x, pkb, part);
  else
    hipLaunchKernelGGL((k1_gemm<32>), dim3(NT / 64, 4), dim3(256), 0, stream,
                       x, pkb, part);
  hipLaunchKernelGGL(k2b_topk, dim3(NCHUNK), dim3(64), 0, stream,
                     part, out, meT, cntT0, cntT1, rank0, rank1, ks);
  hipLaunchKernelGGL(k3b_scan, dim3(1), dim3(64), 0, stream,
                     cntT0, cntT1, baseT0, baseT1, meT, out);
  hipLaunchKernelGGL(k3c_loc, dim3(NCHUNK), dim3(64), 0, stream,
                     out, baseT0, baseT1, rank0, rank1);
}